// Round 12
// baseline (650.999 us; speedup 1.0000x reference)
//
#include <hip/hip_runtime.h>
#include <hip/hip_cooperative_groups.h>
#include <stdint.h>

namespace cg = cooperative_groups;

#define LN_EPS 1e-5f

// ---------- bf16 helpers (RNE, bit-level) ----------
static __device__ __forceinline__ unsigned short f2bf_bits(float f) {
  union { float f; unsigned u; } v; v.f = f;
  unsigned r = v.u + 0x7FFFu + ((v.u >> 16) & 1u);
  return (unsigned short)(r >> 16);
}
static __device__ __forceinline__ float bf2f(unsigned short h) {
  union { unsigned u; float f; } v; v.u = ((unsigned)h) << 16;
  return v.f;
}

typedef __bf16 bf16x8 __attribute__((ext_vector_type(8)));
typedef float floatx4 __attribute__((ext_vector_type(4)));

typedef __attribute__((address_space(1))) unsigned int* gas_ptr;
typedef __attribute__((address_space(3))) unsigned int* las_ptr;
static __device__ __forceinline__ void async_cp16(const void* g, void* l) {
  __builtin_amdgcn_global_load_lds((gas_ptr)g, (las_ptr)l, 16, 0, 0);
}

// =====================================================================================
// Cooperative mega-kernel: all 7 pipeline phases in one launch, grid.sync() between.
// Grid-stride everywhere; no thread ever returns before the last phase it must sync.
// SMEM (33792 B) re-carved per phase: gemm panels / perm scan / gmax vector.
// =====================================================================================
__global__ __launch_bounds__(256, 3) void mega_kernel(
    const float* __restrict__ points, const int* __restrict__ mask,
    const float* __restrict__ w1, const float* __restrict__ g1,
    const float* __restrict__ be1, const float* __restrict__ w2,
    const float* __restrict__ b2, const float* __restrict__ w3,
    const float* __restrict__ g2, const float* __restrict__ be2,
    const float* __restrict__ w4, const float* __restrict__ b4,
    float* __restrict__ out,
    unsigned short* __restrict__ h2, unsigned short* __restrict__ h46,
    unsigned short* __restrict__ w2b, unsigned short* __restrict__ w4b,
    unsigned short* __restrict__ w23b, float* __restrict__ vecb,
    float* __restrict__ pg, float* __restrict__ cvec, float* __restrict__ pmax,
    int* __restrict__ cnt, int* __restrict__ newrow) {
  cg::grid_group grid = cg::this_grid();
  __shared__ __align__(16) char SMEM[33792];
  const int tid = threadIdx.x;
  const int lane = tid & 63;
  const int w = tid >> 6;

  // ======== Phase 0: perm (visible-first compaction map), 32 virtual blocks ========
  for (int b = blockIdx.x; b < 32; b += gridDim.x) {
    int* wsum = (int*)SMEM;          // [4]
    int* woff = ((int*)SMEM) + 4;    // [4]
    int* stot = ((int*)SMEM) + 8;    // [1]
    const int base = b * 4096 + tid * 16;
    int v[16]; int s = 0;
#pragma unroll
    for (int i = 0; i < 16; ++i) { v[i] = (mask[base + i] != 0); s += v[i]; }
    int scan = s;
    for (int o = 1; o < 64; o <<= 1) { int x = __shfl_up(scan, o); if (lane >= o) scan += x; }
    if (lane == 63) wsum[w] = scan;
    __syncthreads();
    if (tid == 0) {
      int a = 0;
      for (int k = 0; k < 4; ++k) { woff[k] = a; a += wsum[k]; }
      stot[0] = a; cnt[b] = a;
    }
    __syncthreads();
    const int excl = scan - s + woff[w];
    const int total = stot[0];
    int run = 0;
#pragma unroll
    for (int i = 0; i < 16; ++i) {
      const int pos = tid * 16 + i;
      const int visBefore = excl + run;
      newrow[b * 4096 + pos] = v[i] ? visBefore : total + (pos - visBefore);
      run += v[i];
    }
    __syncthreads();
  }
  grid.sync();

  // ======== Phase 1: conv1+LN1+relu -> h2 (compacted) + weight prep, 35200 vblocks ====
  for (int vb = blockIdx.x; vb < 35200; vb += gridDim.x) {
    if (vb >= 32768) {
      const int bb = vb - 32768;
      if (bb < 2176) {              // wconv: w2 (32768) + w4 (524288)
        int idx = bb * 256 + tid;
        if (idx < 32768) w2b[idx] = f2bf_bits(w2[idx]);
        else w4b[idx - 32768] = f2bf_bits(w4[idx - 32768]);
      } else {                      // W23 = w3[:,256:] @ w2  [512x128], 2 rows/vblock
        const int p = (bb - 2176) * 2 + (tid >> 7);
        const int c = tid & 127;
        const float* w3r = w3 + (size_t)p * 512 + 256;
        float s = 0.f;
        for (int k = 0; k < 256; ++k) s += w3r[k] * w2[k * 128 + c];
        w23b[p * 128 + c] = f2bf_bits(s);
        if (c == 0) {
          float vbv = 0.f;
          for (int k = 0; k < 256; ++k) vbv += w3r[k] * b2[k];
          vecb[p] = vbv;
        }
      }
    } else {
      const size_t p = (size_t)vb * 4 + w;
      const int dest = newrow[p];
      const int cntb = cnt[p >> 12];
      const int ceilv = (cntb + 127) & ~127;
      if (dest < ceilv) {
        const bool vis = (dest < cntb);
        const float x0 = points[p * 3 + 0];
        const float x1 = points[p * 3 + 1];
        const float x2 = points[p * 3 + 2];
        const int c0 = lane * 2, c1 = c0 + 1;
        float h00 = w1[c0 * 3] * x0 + w1[c0 * 3 + 1] * x1 + w1[c0 * 3 + 2] * x2;
        float h01 = w1[c1 * 3] * x0 + w1[c1 * 3 + 1] * x1 + w1[c1 * 3 + 2] * x2;
        float s = h00 + h01;
        for (int o = 32; o; o >>= 1) s += __shfl_xor(s, o);
        const float mu = s * (1.f / 128.f);
        const float d0 = h00 - mu, d1 = h01 - mu;
        float q = d0 * d0 + d1 * d1;
        for (int o = 32; o; o >>= 1) q += __shfl_xor(q, o);
        const float rs = rsqrtf(q * (1.f / 128.f) + LN_EPS);
        const float y0 = vis ? fmaxf(d0 * rs * g1[c0] + be1[c0], 0.f) : 0.f;
        const float y1 = vis ? fmaxf(d1 * rs * g1[c1] + be1[c1], 0.f) : 0.f;
        union { unsigned u; unsigned short s2[2]; } pk;
        pk.s2[0] = f2bf_bits(y0);
        pk.s2[1] = f2bf_bits(y1);
        const size_t prow = (p & ~(size_t)4095) + (size_t)dest;
        ((unsigned*)h2)[prow * 64 + lane] = pk.u;
      }
    }
  }
  grid.sync();

  // shared carve for GEMM phases
  char* smA0 = SMEM;
  char* smA1 = SMEM + 8192;
  char* smB0 = SMEM + 16384;
  char* smB1 = SMEM + 24576;
  float* lmax = (float*)(SMEM + 32768);   // [2][128]
  const int wm = w >> 1, wn = w & 1;
  const int fm = lane & 15, fq = lane >> 4;
  const int rSub = lane >> 2;
  const int cb16 = (lane & 3) * 16;
  const int fOff = fm * 64 + fq * 16;

  // ======== Phase 2: gemm23 fused (768-col space, K=128), 6144 tiles ========
  for (int gid = blockIdx.x; gid < 6144; gid += gridDim.x) {
    const int xcd = gid & 7;
    const int slot = gid >> 3;
    const int rowTile = xcd * 128 + slot / 6;
    const int colTile = slot % 6;
    const bool isPG = (colTile < 2);
    const int colBase = isPG ? colTile * 128 : (colTile - 2) * 128;
    const size_t rowBase = (size_t)rowTile * 128;
    const unsigned short* Bw = isPG ? w2b : w23b;
    const int cntb = cnt[rowBase >> 12];
    const int rb = (int)(rowBase & 4095);
    if (rb >= cntb) {
      if (isPG && tid < 128) pg[(size_t)rowTile * 256 + colBase + tid] = b2[colBase + tid];
      continue;
    }
    floatx4 acc[4][4];
    const floatx4 zero = {0.f, 0.f, 0.f, 0.f};
#pragma unroll
    for (int i = 0; i < 4; ++i)
#pragma unroll
      for (int j = 0; j < 4; ++j) acc[i][j] = zero;

    const size_t Kb = 256;   // K=128 bf16
    const char* gA = (const char*)h2 + (rowBase + (size_t)(w * 32 + rSub)) * Kb + cb16;
    const char* gB = (const char*)Bw + ((size_t)colBase + (size_t)(w * 32 + rSub)) * Kb + cb16;
    const size_t skip16 = 16 * Kb;
    char* lA0 = smA0 + w * 2048;
    char* lA1 = smA1 + w * 2048;
    char* lB0 = smB0 + w * 2048;
    char* lB1 = smB1 + w * 2048;
    const char* pa0 = smA0 + wm * 64 * 64 + fOff;
    const char* pa1 = smA1 + wm * 64 * 64 + fOff;
    const char* pb0 = smB0 + wn * 64 * 64 + fOff;
    const char* pb1 = smB1 + wn * 64 * 64 + fOff;

    for (int k0 = 0; k0 < 128; k0 += 64) {
      async_cp16(gA, lA0);
      async_cp16(gA + skip16, lA0 + 1024);
      async_cp16(gA + 64, lA1);
      async_cp16(gA + 64 + skip16, lA1 + 1024);
      async_cp16(gB, lB0);
      async_cp16(gB + skip16, lB0 + 1024);
      async_cp16(gB + 64, lB1);
      async_cp16(gB + 64 + skip16, lB1 + 1024);
      gA += 128; gB += 128;
      __syncthreads();
      bf16x8 af0[4], bg0[4], af1[4], bg1[4];
#pragma unroll
      for (int i = 0; i < 4; ++i) af0[i] = *(const bf16x8*)(pa0 + i * 16 * 64);
#pragma unroll
      for (int j = 0; j < 4; ++j) bg0[j] = *(const bf16x8*)(pb0 + j * 16 * 64);
#pragma unroll
      for (int i = 0; i < 4; ++i)
#pragma unroll
        for (int j = 0; j < 4; ++j)
          acc[i][j] = __builtin_amdgcn_mfma_f32_16x16x32_bf16(af0[i], bg0[j], acc[i][j], 0, 0, 0);
#pragma unroll
      for (int i = 0; i < 4; ++i) af1[i] = *(const bf16x8*)(pa1 + i * 16 * 64);
#pragma unroll
      for (int j = 0; j < 4; ++j) bg1[j] = *(const bf16x8*)(pb1 + j * 16 * 64);
#pragma unroll
      for (int i = 0; i < 4; ++i)
#pragma unroll
        for (int j = 0; j < 4; ++j)
          acc[i][j] = __builtin_amdgcn_mfma_f32_16x16x32_bf16(af1[i], bg1[j], acc[i][j], 0, 0, 0);
      __syncthreads();
    }

    if (isPG) {
      float m4[4] = {-1e30f, -1e30f, -1e30f, -1e30f};
#pragma unroll
      for (int j = 0; j < 4; ++j) {
        const float ex = b2[colBase + wn * 64 + j * 16 + fm];
#pragma unroll
        for (int i = 0; i < 4; ++i)
#pragma unroll
          for (int r = 0; r < 4; ++r) m4[j] = fmaxf(m4[j], acc[i][j][r] + ex);
        m4[j] = fmaxf(m4[j], __shfl_xor(m4[j], 16));
        m4[j] = fmaxf(m4[j], __shfl_xor(m4[j], 32));
      }
      const float sel = (fq == 0) ? m4[0] : (fq == 1) ? m4[1] : (fq == 2) ? m4[2] : m4[3];
      lmax[wm * 128 + wn * 64 + fq * 16 + fm] = sel;
      __syncthreads();
      if (tid < 128) {
        const float v = fmaxf(lmax[tid], lmax[128 + tid]);
        pg[(size_t)rowTile * 256 + colBase + tid] = v;
      }
    } else {
#pragma unroll
      for (int j = 0; j < 4; ++j) {
        const int col = colBase + wn * 64 + j * 16 + fm;
        const float ex = vecb[col];
#pragma unroll
        for (int i = 0; i < 4; ++i) {
          const size_t row0 = rowBase + wm * 64 + i * 16 + fq * 4;
#pragma unroll
          for (int r = 0; r < 4; ++r) {
            h46[(row0 + r) * 512 + col] = f2bf_bits(acc[i][j][r] + ex);
          }
        }
      }
    }
  }
  grid.sync();

  // ======== Phase 3: gmax + cvec (coalesced GEMV), 128 blocks active ========
  if (blockIdx.x < 128) {
    float* gm = (float*)SMEM;   // [256]
    const int b = blockIdx.x >> 2, quarter = blockIdx.x & 3;
    float m = -1e30f;
    for (int s = 0; s < 32; ++s) m = fmaxf(m, pg[((size_t)b * 32 + s) * 256 + tid]);
    gm[tid] = m;
    __syncthreads();
    const float g0 = gm[lane * 4 + 0];
    const float g1v = gm[lane * 4 + 1];
    const float g2v = gm[lane * 4 + 2];
    const float g3 = gm[lane * 4 + 3];
    for (int pp = 0; pp < 32; ++pp) {
      const int p = quarter * 128 + w * 32 + pp;
      const float4 wr = *(const float4*)(w3 + (size_t)p * 512 + lane * 4);
      float s = wr.x * g0 + wr.y * g1v + wr.z * g2v + wr.w * g3;
      for (int o = 32; o; o >>= 1) s += __shfl_xor(s, o);
      if (lane == 0) cvec[b * 512 + p] = s;
    }
  }
  grid.sync();

  // ======== Phase 4: (+cvec) + LN2 + relu in place on h46, 32768 vblocks ========
  for (int vb = blockIdx.x; vb < 32768; vb += gridDim.x) {
    const size_t p = (size_t)vb * 4 + w;
    const int cb = cnt[p >> 12];
    const int pin = (int)(p & 4095);
    const int ceilv = (cb + 127) & ~127;
    if (pin >= ceilv) continue;            // no barrier below — divergent continue safe
    unsigned short* row = h46 + p * 512;
    const int c0 = lane * 8;
    if (pin >= cb) {                        // straddle zero-fill
      const uint4 z = {0, 0, 0, 0};
      *(uint4*)(row + c0) = z;
      continue;
    }
    const int b = (int)(p >> 12);
    union { uint4 v; unsigned short s[8]; } in;
    in.v = *(const uint4*)(row + c0);
    float cv[8];
    *(float4*)(cv) = *(const float4*)(cvec + b * 512 + c0);
    *(float4*)(cv + 4) = *(const float4*)(cvec + b * 512 + c0 + 4);
    float f[8];
    float s = 0.f;
#pragma unroll
    for (int k = 0; k < 8; ++k) { f[k] = bf2f(in.s[k]) + cv[k]; s += f[k]; }
    for (int o = 32; o; o >>= 1) s += __shfl_xor(s, o);
    const float mu = s * (1.f / 512.f);
    float q = 0.f;
#pragma unroll
    for (int k = 0; k < 8; ++k) { const float d = f[k] - mu; q += d * d; }
    for (int o = 32; o; o >>= 1) q += __shfl_xor(q, o);
    const float rs = rsqrtf(q * (1.f / 512.f) + LN_EPS);
    union { uint4 v; unsigned short s[8]; } outv;
#pragma unroll
    for (int k = 0; k < 8; ++k) {
      const float y = fmaxf((f[k] - mu) * rs * g2[c0 + k] + be2[c0 + k], 0.f);
      outv.s[k] = f2bf_bits(y);
    }
    *(uint4*)(row + c0) = outv.v;
  }
  grid.sync();

  // ======== Phase 5: gemm4 colmax(h46 @ w4^T) -> pmax, 8192 tiles, K=512 ========
  for (int gid = blockIdx.x; gid < 8192; gid += gridDim.x) {
    const int xcd = gid & 7;
    const int slot = gid >> 3;
    const int rowTile = xcd * 128 + slot / 8;
    const int colTile = slot % 8;
    const size_t rowBase = (size_t)rowTile * 128;
    const int colBase = colTile * 128;
    const int cntb = cnt[rowBase >> 12];
    const int rb = (int)(rowBase & 4095);
    if (rb >= cntb) {
      if (tid < 128) pmax[(size_t)rowTile * 1024 + colBase + tid] = 0.f;
      continue;
    }
    floatx4 acc[4][4];
    const floatx4 zero = {0.f, 0.f, 0.f, 0.f};
#pragma unroll
    for (int i = 0; i < 4; ++i)
#pragma unroll
      for (int j = 0; j < 4; ++j) acc[i][j] = zero;

    const size_t Kb = 1024;   // K=512 bf16
    const char* gA = (const char*)h46 + (rowBase + (size_t)(w * 32 + rSub)) * Kb + cb16;
    const char* gB = (const char*)w4b + ((size_t)colBase + (size_t)(w * 32 + rSub)) * Kb + cb16;
    const size_t skip16 = 16 * Kb;
    char* lA0 = smA0 + w * 2048;
    char* lA1 = smA1 + w * 2048;
    char* lB0 = smB0 + w * 2048;
    char* lB1 = smB1 + w * 2048;
    const char* pa0 = smA0 + wm * 64 * 64 + fOff;
    const char* pa1 = smA1 + wm * 64 * 64 + fOff;
    const char* pb0 = smB0 + wn * 64 * 64 + fOff;
    const char* pb1 = smB1 + wn * 64 * 64 + fOff;

    for (int k0 = 0; k0 < 512; k0 += 64) {
      async_cp16(gA, lA0);
      async_cp16(gA + skip16, lA0 + 1024);
      async_cp16(gA + 64, lA1);
      async_cp16(gA + 64 + skip16, lA1 + 1024);
      async_cp16(gB, lB0);
      async_cp16(gB + skip16, lB0 + 1024);
      async_cp16(gB + 64, lB1);
      async_cp16(gB + 64 + skip16, lB1 + 1024);
      gA += 128; gB += 128;
      __syncthreads();
      bf16x8 af0[4], bg0[4], af1[4], bg1[4];
#pragma unroll
      for (int i = 0; i < 4; ++i) af0[i] = *(const bf16x8*)(pa0 + i * 16 * 64);
#pragma unroll
      for (int j = 0; j < 4; ++j) bg0[j] = *(const bf16x8*)(pb0 + j * 16 * 64);
#pragma unroll
      for (int i = 0; i < 4; ++i)
#pragma unroll
        for (int j = 0; j < 4; ++j)
          acc[i][j] = __builtin_amdgcn_mfma_f32_16x16x32_bf16(af0[i], bg0[j], acc[i][j], 0, 0, 0);
#pragma unroll
      for (int i = 0; i < 4; ++i) af1[i] = *(const bf16x8*)(pa1 + i * 16 * 64);
#pragma unroll
      for (int j = 0; j < 4; ++j) bg1[j] = *(const bf16x8*)(pb1 + j * 16 * 64);
#pragma unroll
      for (int i = 0; i < 4; ++i)
#pragma unroll
        for (int j = 0; j < 4; ++j)
          acc[i][j] = __builtin_amdgcn_mfma_f32_16x16x32_bf16(af1[i], bg1[j], acc[i][j], 0, 0, 0);
      __syncthreads();
    }

    float m4[4] = {-1e30f, -1e30f, -1e30f, -1e30f};
#pragma unroll
    for (int j = 0; j < 4; ++j) {
#pragma unroll
      for (int i = 0; i < 4; ++i)
#pragma unroll
        for (int r = 0; r < 4; ++r) m4[j] = fmaxf(m4[j], acc[i][j][r]);
      m4[j] = fmaxf(m4[j], __shfl_xor(m4[j], 16));
      m4[j] = fmaxf(m4[j], __shfl_xor(m4[j], 32));
    }
    const float sel = (fq == 0) ? m4[0] : (fq == 1) ? m4[1] : (fq == 2) ? m4[2] : m4[3];
    lmax[wm * 128 + wn * 64 + fq * 16 + fm] = sel;
    __syncthreads();
    if (tid < 128) {
      const float v = fmaxf(lmax[tid], lmax[128 + tid]);
      pmax[(size_t)rowTile * 1024 + colBase + tid] = v;
    }
  }
  grid.sync();

  // ======== Phase 6: final reduce, 128 vblocks ========
  for (int vb = blockIdx.x; vb < 128; vb += gridDim.x) {
    const int idx = vb * 256 + tid;
    const int b = idx >> 10, f = idx & 1023;
    float m = -1e30f;
    for (int r = 0; r < 32; ++r) m = fmaxf(m, pmax[((size_t)(b * 32 + r)) * 1024 + f]);
    out[idx] = m + b4[f];
  }
}

// =====================================================================================
extern "C" void kernel_launch(void* const* d_in, const int* in_sizes, int n_in,
                              void* d_out, int out_size, void* d_ws, size_t ws_size,
                              hipStream_t stream) {
  const float* points = (const float*)d_in[0];
  const int* mask = (const int*)d_in[1];
  const float* w1 = (const float*)d_in[2];
  const float* g1 = (const float*)d_in[3];
  const float* be1 = (const float*)d_in[4];
  const float* w2 = (const float*)d_in[5];
  const float* b2 = (const float*)d_in[6];
  const float* w3 = (const float*)d_in[7];
  const float* g2 = (const float*)d_in[8];
  const float* be2 = (const float*)d_in[9];
  const float* w4 = (const float*)d_in[10];
  const float* b4 = (const float*)d_in[11];
  float* out = (float*)d_out;
  char* ws = (char*)d_ws;

  const size_t OFF_H46 = 0;                          // 134217728 B (bf16 131072x512)
  const size_t OFF_H2 = 134217728;                   //  33554432 B (bf16 131072x128)
  const size_t OFF_W2B = OFF_H2 + 33554432;          //     65536 B
  const size_t OFF_W4B = OFF_W2B + 65536;            //   1048576 B
  const size_t OFF_W23B = OFF_W4B + 1048576;         //    131072 B (bf16 512x128)
  const size_t OFF_VECB = OFF_W23B + 131072;         //      2048 B (f32 512)
  const size_t OFF_PG = OFF_VECB + 2048;             //   1048576 B (f32 1024x256)
  const size_t OFF_CVEC = OFF_PG + 1048576;          //     65536 B
  const size_t OFF_PMAX = OFF_CVEC + 65536;          //   4194304 B
  const size_t OFF_CNT = OFF_PMAX + 4194304;         //      4096 B
  const size_t OFF_NEWROW = OFF_CNT + 4096;          //    524288 B (~167 MB total)

  unsigned short* h2 = (unsigned short*)(ws + OFF_H2);
  unsigned short* h46 = (unsigned short*)(ws + OFF_H46);
  unsigned short* w2b = (unsigned short*)(ws + OFF_W2B);
  unsigned short* w4b = (unsigned short*)(ws + OFF_W4B);
  unsigned short* w23b = (unsigned short*)(ws + OFF_W23B);
  float* vecb = (float*)(ws + OFF_VECB);
  float* pg = (float*)(ws + OFF_PG);
  float* cvecp = (float*)(ws + OFF_CVEC);
  float* pmaxp = (float*)(ws + OFF_PMAX);
  int* cntp = (int*)(ws + OFF_CNT);
  int* newrow = (int*)(ws + OFF_NEWROW);

  // occupancy-sized cooperative grid (multiple of 256 -> multiple of 8 for XCD banding)
  int maxB = 0;
  hipOccupancyMaxActiveBlocksPerMultiprocessor(&maxB, mega_kernel, 256, 0);
  if (maxB < 1) maxB = 1;
  if (maxB > 4) maxB = 4;
  int grid = maxB * 256;

  void* args[] = {
    (void*)&points, (void*)&mask, (void*)&w1, (void*)&g1, (void*)&be1,
    (void*)&w2, (void*)&b2, (void*)&w3, (void*)&g2, (void*)&be2,
    (void*)&w4, (void*)&b4, (void*)&out,
    (void*)&h2, (void*)&h46, (void*)&w2b, (void*)&w4b, (void*)&w23b, (void*)&vecb,
    (void*)&pg, (void*)&cvecp, (void*)&pmaxp, (void*)&cntp, (void*)&newrow
  };
  hipLaunchCooperativeKernel((void*)mega_kernel, dim3(grid), dim3(256), args, 0, stream);
}

// Round 13
// 275.830 us; speedup vs baseline: 2.3601x; 2.3601x over previous
//
#include <hip/hip_runtime.h>
#include <stdint.h>

#define LN_EPS 1e-5f

// ---------- bf16 helpers (RNE, bit-level) ----------
static __device__ __forceinline__ unsigned short f2bf_bits(float f) {
  union { float f; unsigned u; } v; v.f = f;
  unsigned r = v.u + 0x7FFFu + ((v.u >> 16) & 1u);
  return (unsigned short)(r >> 16);
}
static __device__ __forceinline__ float bf2f(unsigned short h) {
  union { unsigned u; float f; } v; v.u = ((unsigned)h) << 16;
  return v.f;
}

typedef __bf16 bf16x8 __attribute__((ext_vector_type(8)));
typedef float floatx4 __attribute__((ext_vector_type(4)));

// ---------- async global->LDS, 16B per lane ----------
typedef __attribute__((address_space(1))) unsigned int* gas_ptr;
typedef __attribute__((address_space(3))) unsigned int* las_ptr;
static __device__ __forceinline__ void async_cp16(const void* g, void* l) {
  __builtin_amdgcn_global_load_lds((gas_ptr)g, (las_ptr)l, 16, 0, 0);
}

// =====================================================================================
// perm: per batch, stable partition visible-first. newrow[b*4096+n] = within-batch
// destination row; cnt[b] = #visible.
// =====================================================================================
__global__ __launch_bounds__(256) void perm_kernel(
    const int* __restrict__ mask, int* __restrict__ newrow, int* __restrict__ cnt) {
  const int b = blockIdx.x, t = threadIdx.x;
  const int base = b * 4096 + t * 16;
  int v[16]; int s = 0;
#pragma unroll
  for (int i = 0; i < 16; ++i) { v[i] = (mask[base + i] != 0); s += v[i]; }
  const int lane = t & 63, wv = t >> 6;
  int scan = s;
  for (int o = 1; o < 64; o <<= 1) { int x = __shfl_up(scan, o); if (lane >= o) scan += x; }
  __shared__ int wsum[4], woff[4], stotal;
  if (lane == 63) wsum[wv] = scan;
  __syncthreads();
  if (t == 0) { int a = 0; for (int k = 0; k < 4; ++k) { woff[k] = a; a += wsum[k]; } stotal = a; cnt[b] = a; }
  __syncthreads();
  const int excl = scan - s + woff[wv];
  const int total = stotal;
  int run = 0;
#pragma unroll
  for (int i = 0; i < 16; ++i) {
    const int pos = t * 16 + i;
    const int visBefore = excl + run;
    newrow[b * 4096 + pos] = v[i] ? visBefore : total + (pos - visBefore);
    run += v[i];
  }
}

// =====================================================================================
// K_b: conv1 (K=3, fp32 exact) + LayerNorm(128) + mask + relu -> h2 bf16, compacted
// scatter via newrow; visibility == (dest < cnt[b]).
// Block tail 1 [32768, 32768+2176): fp32->bf16 for w2, w4.
// Block tail 2 [34944, 34944+256): W23 = w3R@w2 (fp32, ->bf16) and vecb = w3R@b2.
// =====================================================================================
__global__ __launch_bounds__(256) void conv1_ln_kernel(
    const float* __restrict__ points,
    const float* __restrict__ w1, const float* __restrict__ g1,
    const float* __restrict__ be1, unsigned short* __restrict__ h2,
    const int* __restrict__ newrow, const int* __restrict__ cnt,
    const float* __restrict__ w2, const float* __restrict__ b2,
    const float* __restrict__ w3, const float* __restrict__ w4,
    unsigned short* __restrict__ w2b, unsigned short* __restrict__ w4b,
    unsigned short* __restrict__ w23b, float* __restrict__ vecb) {
  if (blockIdx.x >= 32768) {
    const int bb = blockIdx.x - 32768;
    if (bb < 2176) {              // wconv: w2 (32768) + w4 (524288)
      int idx = bb * 256 + threadIdx.x;
      if (idx < 32768) w2b[idx] = f2bf_bits(w2[idx]);
      else w4b[idx - 32768] = f2bf_bits(w4[idx - 32768]);
    } else {                      // W23 = w3[:,256:] @ w2  [512x128], 2 rows per block
      const int tid = threadIdx.x;
      const int p = (bb - 2176) * 2 + (tid >> 7);
      const int c = tid & 127;
      const float* w3r = w3 + (size_t)p * 512 + 256;
      float s = 0.f;
      for (int k = 0; k < 256; ++k) s += w3r[k] * w2[k * 128 + c];
      w23b[p * 128 + c] = f2bf_bits(s);
      if (c == 0) {
        float vb = 0.f;
        for (int k = 0; k < 256; ++k) vb += w3r[k] * b2[k];
        vecb[p] = vb;
      }
    }
    return;
  }
  const int lane = threadIdx.x & 63;
  const int wv = threadIdx.x >> 6;
  const size_t p = (size_t)blockIdx.x * 4 + wv;
  const int dest = newrow[p];
  const int cntb = cnt[p >> 12];
  const int ceilv = (cntb + 127) & ~127;
  if (dest >= ceilv) return;                 // row never read downstream
  const bool vis = (dest < cntb);
  const float x0 = points[p * 3 + 0];
  const float x1 = points[p * 3 + 1];
  const float x2 = points[p * 3 + 2];
  const int c0 = lane * 2, c1 = c0 + 1;
  float h00 = w1[c0 * 3] * x0 + w1[c0 * 3 + 1] * x1 + w1[c0 * 3 + 2] * x2;
  float h01 = w1[c1 * 3] * x0 + w1[c1 * 3 + 1] * x1 + w1[c1 * 3 + 2] * x2;
  float s = h00 + h01;
  for (int o = 32; o; o >>= 1) s += __shfl_xor(s, o);
  const float mu = s * (1.f / 128.f);
  const float d0 = h00 - mu, d1 = h01 - mu;
  float q = d0 * d0 + d1 * d1;
  for (int o = 32; o; o >>= 1) q += __shfl_xor(q, o);
  const float rs = rsqrtf(q * (1.f / 128.f) + LN_EPS);
  const float y0 = vis ? fmaxf(d0 * rs * g1[c0] + be1[c0], 0.f) : 0.f;
  const float y1 = vis ? fmaxf(d1 * rs * g1[c1] + be1[c1], 0.f) : 0.f;
  union { unsigned u; unsigned short s2[2]; } pk;
  pk.s2[0] = f2bf_bits(y0);
  pk.s2[1] = f2bf_bits(y1);
  const size_t prow = (p & ~(size_t)4095) + (size_t)dest;
  ((unsigned*)h2)[prow * 64 + lane] = pk.u;
}

// =====================================================================================
// gemm23_fused: ONE launch over combined 768-col space, A = h2 [M x 128], BK=64 twin
// panels, 128x128 tiles, XCD bands. colTile 0-1 (PG mode): colmax(h2@w2^T + b2) -> pg,
// nothing stored. colTile 2-5 (OUT mode): h46 = h2@W23^T + vecb. All branching
// block-uniform. Skip tiles: PG -> pg=b2; OUT -> return (ln2 fills straddle).
// =====================================================================================
__global__ __launch_bounds__(256) void gemm23_fused(
    const unsigned short* __restrict__ A,
    const unsigned short* __restrict__ w2b, const unsigned short* __restrict__ w23b,
    unsigned short* __restrict__ h46, float* __restrict__ pg,
    const float* __restrict__ b2, const float* __restrict__ vecb,
    const int* __restrict__ cnt, int M) {
  __shared__ __align__(16) char smA[2][128 * 64];
  __shared__ __align__(16) char smB[2][128 * 64];
  __shared__ float lmax[2][128];

  const int tid = threadIdx.x;
  const int lane = tid & 63;
  const int w = tid >> 6;
  const int wm = w >> 1, wn = w & 1;

  const int gid = blockIdx.x;
  const int xcd = gid & 7;
  const int slot = gid >> 3;
  const int rowsPerXcd = (M >> 7) >> 3;
  const int rowTile = xcd * rowsPerXcd + slot / 6;
  const int colTile = slot % 6;
  const bool isPG = (colTile < 2);
  const int colBase = isPG ? colTile * 128 : (colTile - 2) * 128;
  const size_t rowBase = (size_t)rowTile * 128;
  const unsigned short* Bw = isPG ? w2b : w23b;

  const int cntb = cnt[rowBase >> 12];
  const int rb = (int)(rowBase & 4095);
  if (rb >= cntb) {
    if (isPG) {
      if (tid < 128) pg[(size_t)rowTile * 256 + colBase + tid] = b2[colBase + tid];
    }
    return;
  }

  floatx4 acc[4][4];
  const floatx4 zero = {0.f, 0.f, 0.f, 0.f};
#pragma unroll
  for (int i = 0; i < 4; ++i)
#pragma unroll
    for (int j = 0; j < 4; ++j) acc[i][j] = zero;

  const int rSub = lane >> 2;
  const int cb16 = (lane & 3) * 16;
  const size_t Kb = 256;   // K=128 bf16
  const char* gA = (const char*)A + (rowBase + (size_t)(w * 32 + rSub)) * Kb + cb16;
  const char* gB = (const char*)Bw + ((size_t)colBase + (size_t)(w * 32 + rSub)) * Kb + cb16;
  char* lA0 = smA[0] + w * 2048;
  char* lA1 = smA[1] + w * 2048;
  char* lB0 = smB[0] + w * 2048;
  char* lB1 = smB[1] + w * 2048;
  const size_t skip16 = 16 * Kb;

  const int fm = lane & 15, fq = lane >> 4;
  const int fOff = fm * 64 + fq * 16;
  const char* pa0 = smA[0] + wm * 64 * 64 + fOff;
  const char* pa1 = smA[1] + wm * 64 * 64 + fOff;
  const char* pb0 = smB[0] + wn * 64 * 64 + fOff;
  const char* pb1 = smB[1] + wn * 64 * 64 + fOff;

  for (int k0 = 0; k0 < 128; k0 += 64) {
    async_cp16(gA, lA0);
    async_cp16(gA + skip16, lA0 + 1024);
    async_cp16(gA + 64, lA1);
    async_cp16(gA + 64 + skip16, lA1 + 1024);
    async_cp16(gB, lB0);
    async_cp16(gB + skip16, lB0 + 1024);
    async_cp16(gB + 64, lB1);
    async_cp16(gB + 64 + skip16, lB1 + 1024);
    gA += 128; gB += 128;
    __syncthreads();
    bf16x8 af0[4], bg0[4], af1[4], bg1[4];
#pragma unroll
    for (int i = 0; i < 4; ++i) af0[i] = *(const bf16x8*)(pa0 + i * 16 * 64);
#pragma unroll
    for (int j = 0; j < 4; ++j) bg0[j] = *(const bf16x8*)(pb0 + j * 16 * 64);
#pragma unroll
    for (int i = 0; i < 4; ++i)
#pragma unroll
      for (int j = 0; j < 4; ++j)
        acc[i][j] = __builtin_amdgcn_mfma_f32_16x16x32_bf16(af0[i], bg0[j], acc[i][j], 0, 0, 0);
#pragma unroll
    for (int i = 0; i < 4; ++i) af1[i] = *(const bf16x8*)(pa1 + i * 16 * 64);
#pragma unroll
    for (int j = 0; j < 4; ++j) bg1[j] = *(const bf16x8*)(pb1 + j * 16 * 64);
#pragma unroll
    for (int i = 0; i < 4; ++i)
#pragma unroll
      for (int j = 0; j < 4; ++j)
        acc[i][j] = __builtin_amdgcn_mfma_f32_16x16x32_bf16(af1[i], bg1[j], acc[i][j], 0, 0, 0);
    __syncthreads();
  }

  if (isPG) {       // colmax(acc + b2), no dense store
    float m4[4] = {-1e30f, -1e30f, -1e30f, -1e30f};
#pragma unroll
    for (int j = 0; j < 4; ++j) {
      const float ex = b2[colBase + wn * 64 + j * 16 + fm];
#pragma unroll
      for (int i = 0; i < 4; ++i)
#pragma unroll
        for (int r = 0; r < 4; ++r) m4[j] = fmaxf(m4[j], acc[i][j][r] + ex);
      m4[j] = fmaxf(m4[j], __shfl_xor(m4[j], 16));
      m4[j] = fmaxf(m4[j], __shfl_xor(m4[j], 32));
    }
    const float sel = (fq == 0) ? m4[0] : (fq == 1) ? m4[1] : (fq == 2) ? m4[2] : m4[3];
    lmax[wm][wn * 64 + fq * 16 + fm] = sel;
    __syncthreads();
    if (tid < 128) {
      const float v = fmaxf(lmax[0][tid], lmax[1][tid]);
      pg[(size_t)rowTile * 256 + colBase + tid] = v;
    }
  } else {          // h46 = acc + vecb
#pragma unroll
    for (int j = 0; j < 4; ++j) {
      const int col = colBase + wn * 64 + j * 16 + fm;
      const float ex = vecb[col];
#pragma unroll
      for (int i = 0; i < 4; ++i) {
        const size_t row0 = rowBase + wm * 64 + i * 16 + fq * 4;
#pragma unroll
        for (int r = 0; r < 4; ++r) {
          h46[(row0 + r) * 512 + col] = f2bf_bits(acc[i][j][r] + ex);
        }
      }
    }
  }
}

// =====================================================================================
// GEMM4: colmax(h46 @ w4^T) -> pmax. 128x128, BK=64 twin panels, A+B via cp16->LDS,
// XCD bands. Skip tiles -> 0.
// =====================================================================================
template <int NCT>
__global__ __launch_bounds__(256) void gemm4_kernel(
    const unsigned short* __restrict__ A, const unsigned short* __restrict__ Bw,
    float* __restrict__ outp2, const int* __restrict__ cnt,
    int M, int N, int K) {
  __shared__ __align__(16) char smA[2][128 * 64];
  __shared__ __align__(16) char smB[2][128 * 64];
  __shared__ float lmax[2][128];

  const int tid = threadIdx.x;
  const int lane = tid & 63;
  const int w = tid >> 6;
  const int wm = w >> 1, wn = w & 1;

  const int gid = blockIdx.x;
  const int xcd = gid & 7;
  const int slot = gid >> 3;
  const int rowsPerXcd = (M >> 7) >> 3;
  const int rowTile = xcd * rowsPerXcd + slot / NCT;
  const int colTile = slot % NCT;
  const size_t rowBase = (size_t)rowTile * 128;
  const int colBase = colTile * 128;

  const int cntb = cnt[rowBase >> 12];
  const int rb = (int)(rowBase & 4095);
  if (rb >= cntb) {
    if (tid < 128) outp2[(size_t)rowTile * N + colBase + tid] = 0.f;
    return;
  }

  floatx4 acc[4][4];
  const floatx4 zero = {0.f, 0.f, 0.f, 0.f};
#pragma unroll
  for (int i = 0; i < 4; ++i)
#pragma unroll
    for (int j = 0; j < 4; ++j) acc[i][j] = zero;

  const int rSub = lane >> 2;
  const int cb16 = (lane & 3) * 16;
  const size_t Kb = (size_t)K * 2;
  const char* gA = (const char*)A + (rowBase + (size_t)(w * 32 + rSub)) * Kb + cb16;
  const char* gB = (const char*)Bw + ((size_t)colBase + (size_t)(w * 32 + rSub)) * Kb + cb16;
  char* lA0 = smA[0] + w * 2048;
  char* lA1 = smA[1] + w * 2048;
  char* lB0 = smB[0] + w * 2048;
  char* lB1 = smB[1] + w * 2048;
  const size_t skip16 = 16 * Kb;

  const int fm = lane & 15, fq = lane >> 4;
  const int fOff = fm * 64 + fq * 16;
  const char* pa0 = smA[0] + wm * 64 * 64 + fOff;
  const char* pa1 = smA[1] + wm * 64 * 64 + fOff;
  const char* pb0 = smB[0] + wn * 64 * 64 + fOff;
  const char* pb1 = smB[1] + wn * 64 * 64 + fOff;

  for (int k0 = 0; k0 < K; k0 += 64) {
    async_cp16(gA, lA0);
    async_cp16(gA + skip16, lA0 + 1024);
    async_cp16(gA + 64, lA1);
    async_cp16(gA + 64 + skip16, lA1 + 1024);
    async_cp16(gB, lB0);
    async_cp16(gB + skip16, lB0 + 1024);
    async_cp16(gB + 64, lB1);
    async_cp16(gB + 64 + skip16, lB1 + 1024);
    gA += 128; gB += 128;
    __syncthreads();
    bf16x8 af0[4], bg0[4], af1[4], bg1[4];
#pragma unroll
    for (int i = 0; i < 4; ++i) af0[i] = *(const bf16x8*)(pa0 + i * 16 * 64);
#pragma unroll
    for (int j = 0; j < 4; ++j) bg0[j] = *(const bf16x8*)(pb0 + j * 16 * 64);
#pragma unroll
    for (int i = 0; i < 4; ++i)
#pragma unroll
      for (int j = 0; j < 4; ++j)
        acc[i][j] = __builtin_amdgcn_mfma_f32_16x16x32_bf16(af0[i], bg0[j], acc[i][j], 0, 0, 0);
#pragma unroll
    for (int i = 0; i < 4; ++i) af1[i] = *(const bf16x8*)(pa1 + i * 16 * 64);
#pragma unroll
    for (int j = 0; j < 4; ++j) bg1[j] = *(const bf16x8*)(pb1 + j * 16 * 64);
#pragma unroll
    for (int i = 0; i < 4; ++i)
#pragma unroll
      for (int j = 0; j < 4; ++j)
        acc[i][j] = __builtin_amdgcn_mfma_f32_16x16x32_bf16(af1[i], bg1[j], acc[i][j], 0, 0, 0);
    __syncthreads();
  }

  float m4[4] = {-1e30f, -1e30f, -1e30f, -1e30f};
#pragma unroll
  for (int j = 0; j < 4; ++j) {
#pragma unroll
    for (int i = 0; i < 4; ++i)
#pragma unroll
      for (int r = 0; r < 4; ++r) m4[j] = fmaxf(m4[j], acc[i][j][r]);
    m4[j] = fmaxf(m4[j], __shfl_xor(m4[j], 16));
    m4[j] = fmaxf(m4[j], __shfl_xor(m4[j], 32));
  }
  const float sel = (fq == 0) ? m4[0] : (fq == 1) ? m4[1] : (fq == 2) ? m4[2] : m4[3];
  lmax[wm][wn * 64 + fq * 16 + fm] = sel;
  __syncthreads();
  if (tid < 128) {
    const float v = fmaxf(lmax[0][tid], lmax[1][tid]);
    outp2[(size_t)rowTile * N + colBase + tid] = v;
  }
}

// =====================================================================================
// Fused gmax reduce + cvec, COALESCED GEMV. 128 blocks (4/batch). Per block:
// gm[t] = max over 32 pg partials (coalesced); then wave-per-row dot: lane holds
// w3[p][lane*4..+4] (float4, coalesced) x gm (from LDS), shuffle-reduce over 64.
// =====================================================================================
__global__ __launch_bounds__(256) void gmax_cvec_kernel(
    const float* __restrict__ pg, const float* __restrict__ w3,
    float* __restrict__ cvec) {
  __shared__ float gm[256];
  const int b = blockIdx.x >> 2, quarter = blockIdx.x & 3;
  const int t = threadIdx.x;
  float m = -1e30f;
  for (int s = 0; s < 32; ++s) m = fmaxf(m, pg[((size_t)b * 32 + s) * 256 + t]);
  gm[t] = m;
  __syncthreads();
  const int lane = t & 63, wv = t >> 6;
  const float g0 = gm[lane * 4 + 0];
  const float g1 = gm[lane * 4 + 1];
  const float g2v = gm[lane * 4 + 2];
  const float g3 = gm[lane * 4 + 3];
  for (int pp = 0; pp < 32; ++pp) {
    const int p = quarter * 128 + wv * 32 + pp;
    const float4 wr = *(const float4*)(w3 + (size_t)p * 512 + lane * 4);
    float s = wr.x * g0 + wr.y * g1 + wr.z * g2v + wr.w * g3;
    for (int o = 32; o; o >>= 1) s += __shfl_xor(s, o);
    if (lane == 0) cvec[b * 512 + p] = s;
  }
}

// =====================================================================================
// K_h: (+cvec) + LayerNorm(512) + relu in place on h46 (compacted).
// rows < cnt: h4 = h46 + cvec[b], LN+relu; rows in [cnt, ceil128): zero;
// rows >= ceil128: untouched (no readers).
// =====================================================================================
__global__ __launch_bounds__(256) void ln2_kernel(
    unsigned short* __restrict__ h46, const int* __restrict__ cnt,
    const float* __restrict__ cvec,
    const float* __restrict__ g2, const float* __restrict__ be2) {
  const int lane = threadIdx.x & 63;
  const int wv = threadIdx.x >> 6;
  const size_t p = (size_t)blockIdx.x * 4 + wv;
  const int cb = cnt[p >> 12];
  const int pin = (int)(p & 4095);
  const int ceilv = (cb + 127) & ~127;
  if (pin >= ceilv) return;
  unsigned short* row = h46 + p * 512;
  const int c0 = lane * 8;
  if (pin >= cb) {                            // straddle zero-fill
    const uint4 z = {0, 0, 0, 0};
    *(uint4*)(row + c0) = z;
    return;
  }
  const int b = (int)(p >> 12);
  union { uint4 v; unsigned short s[8]; } in;
  in.v = *(const uint4*)(row + c0);
  float cv[8];
  *(float4*)(cv) = *(const float4*)(cvec + b * 512 + c0);
  *(float4*)(cv + 4) = *(const float4*)(cvec + b * 512 + c0 + 4);
  float f[8];
  float s = 0.f;
#pragma unroll
  for (int k = 0; k < 8; ++k) { f[k] = bf2f(in.s[k]) + cv[k]; s += f[k]; }
  for (int o = 32; o; o >>= 1) s += __shfl_xor(s, o);
  const float mu = s * (1.f / 512.f);
  float q = 0.f;
#pragma unroll
  for (int k = 0; k < 8; ++k) { const float d = f[k] - mu; q += d * d; }
  for (int o = 32; o; o >>= 1) q += __shfl_xor(q, o);
  const float rs = rsqrtf(q * (1.f / 512.f) + LN_EPS);
  union { uint4 v; unsigned short s[8]; } outv;
#pragma unroll
  for (int k = 0; k < 8; ++k) {
    const float y = fmaxf((f[k] - mu) * rs * g2[c0 + k] + be2[c0 + k], 0.f);
    outv.s[k] = f2bf_bits(y);
  }
  *(uint4*)(row + c0) = outv.v;
}

// =====================================================================================
// K_j: out[b][f] = max over 32 row-blocks of pmax + b4[f]
// =====================================================================================
__global__ __launch_bounds__(256) void final_kernel(
    const float* __restrict__ pmax, const float* __restrict__ b4,
    float* __restrict__ out) {
  const int idx = blockIdx.x * 256 + threadIdx.x;
  const int b = idx >> 10, f = idx & 1023;
  float m = -1e30f;
  for (int r = 0; r < 32; ++r) m = fmaxf(m, pmax[((size_t)(b * 32 + r)) * 1024 + f]);
  out[idx] = m + b4[f];
}

// =====================================================================================
extern "C" void kernel_launch(void* const* d_in, const int* in_sizes, int n_in,
                              void* d_out, int out_size, void* d_ws, size_t ws_size,
                              hipStream_t stream) {
  const float* points = (const float*)d_in[0];
  const int* mask = (const int*)d_in[1];
  const float* w1 = (const float*)d_in[2];
  const float* g1 = (const float*)d_in[3];
  const float* be1 = (const float*)d_in[4];
  const float* w2 = (const float*)d_in[5];
  const float* b2 = (const float*)d_in[6];
  const float* w3 = (const float*)d_in[7];
  const float* g2 = (const float*)d_in[8];
  const float* be2 = (const float*)d_in[9];
  const float* w4 = (const float*)d_in[10];
  const float* b4 = (const float*)d_in[11];
  float* out = (float*)d_out;
  char* ws = (char*)d_ws;

  const size_t OFF_H46 = 0;                          // 134217728 B (bf16 131072x512)
  const size_t OFF_H2 = 134217728;                   //  33554432 B (bf16 131072x128)
  const size_t OFF_W2B = OFF_H2 + 33554432;          //     65536 B
  const size_t OFF_W4B = OFF_W2B + 65536;            //   1048576 B
  const size_t OFF_W23B = OFF_W4B + 1048576;         //    131072 B (bf16 512x128)
  const size_t OFF_VECB = OFF_W23B + 131072;         //      2048 B (f32 512)
  const size_t OFF_PG = OFF_VECB + 2048;             //   1048576 B (f32 1024x256)
  const size_t OFF_CVEC = OFF_PG + 1048576;          //     65536 B
  const size_t OFF_PMAX = OFF_CVEC + 65536;          //   4194304 B
  const size_t OFF_CNT = OFF_PMAX + 4194304;         //      4096 B
  const size_t OFF_NEWROW = OFF_CNT + 4096;          //    524288 B (~167 MB total)

  unsigned short* h2 = (unsigned short*)(ws + OFF_H2);
  unsigned short* h46 = (unsigned short*)(ws + OFF_H46);
  unsigned short* w2b = (unsigned short*)(ws + OFF_W2B);
  unsigned short* w4b = (unsigned short*)(ws + OFF_W4B);
  unsigned short* w23b = (unsigned short*)(ws + OFF_W23B);
  float* vecb = (float*)(ws + OFF_VECB);
  float* pg = (float*)(ws + OFF_PG);
  float* cvecp = (float*)(ws + OFF_CVEC);
  float* pmaxp = (float*)(ws + OFF_PMAX);
  int* cntp = (int*)(ws + OFF_CNT);
  int* newrow = (int*)(ws + OFF_NEWROW);

  // 0. visible-first compaction map per batch
  perm_kernel<<<32, 256, 0, stream>>>(mask, newrow, cntp);
  // 1. conv1+LN1+relu -> h2 (compacted); tails: wconv (w2,w4) + W23/vecb precompute
  conv1_ln_kernel<<<32768 + 2176 + 256, 256, 0, stream>>>(
      points, w1, g1, be1, h2, newrow, cntp, w2, b2, w3, w4, w2b, w4b, w23b, vecb);
  // 2. fused: pg = colmax(h2@w2^T + b2)  AND  h46 = h2@W23^T + vecb  (one launch)
  gemm23_fused<<<6144, 256, 0, stream>>>(h2, w2b, w23b, h46, pg, b2, vecb, cntp, 131072);
  // 3. gmax + cvec (coalesced GEMV, 128 blocks)
  gmax_cvec_kernel<<<128, 256, 0, stream>>>(pg, w3, cvecp);
  // 4. (+cvec) + LN2 + relu in place; zero straddle rows [cnt, ceil128)
  ln2_kernel<<<32768, 256, 0, stream>>>(h46, cntp, cvecp, g2, be2);
  // 5. h7 colmax -> pmax (skip tiles write 0)
  gemm4_kernel<8><<<8192, 256, 0, stream>>>(h46, w4b, pmaxp, cntp, 131072, 1024, 512);
  // 6. out = max over row-blocks + b4
  final_kernel<<<128, 256, 0, stream>>>(pmaxp, b4, out);
}